// Round 8
// baseline (202.705 us; speedup 1.0000x reference)
//
#include <hip/hip_runtime.h>
#include <cstddef>

#define NT 10            // NUM_TOKENS
#define TD 96            // TOKEN_DIM == REF_DIM
#define NH 4             // NUM_HEADS
#define NPOS (32 * 2048) // B*T positions
#define TPB 256
#define LPP 8            // lanes per position
#define XPL 12           // x elems per lane (TD / LPP)

// workspace layout (bytes)
#define WS_WQ 0          // h2    wqH[96][48]            (18432 B) -> staged to LDS
#define WS_KVW 18432     // float kvw[96][16]             ( 6144 B) -> read via L1
                         //   row d: [wv0..3 | kv0..9 | pad pad]
#define WS_BYTES 24576

typedef _Float16 h2 __attribute__((ext_vector_type(2)));

__device__ __forceinline__ h2 pack_h2(float a, float b) {
    return __builtin_bit_cast(h2, __builtin_amdgcn_cvt_pkrtz(a, b));
}

__device__ __forceinline__ float fast_tanh(float x) {
    // tanh(x) = 1 - 2/(exp(2x)+1); exact limits at +/-inf, ~1e-6 rel error
    float e = __expf(2.0f * x);
    return 1.0f - 2.0f * __builtin_amdgcn_rcpf(e + 1.0f);
}

__device__ __forceinline__ float dot2acc(h2 a, h2 b, float c) {
#if __has_builtin(__builtin_amdgcn_fdot2)
    return __builtin_amdgcn_fdot2(a, b, c, false);
#else
    c = fmaf((float)a[0], (float)b[0], c);
    return fmaf((float)a[1], (float)b[1], c);
#endif
}

// ---- prep kernel: 48 blocks, block b owns d-slice [2b, 2b+2) ----
__global__ __launch_bounds__(256) void gst_prep(
    const float* __restrict__ tokens,
    const float* __restrict__ Wq,
    const float* __restrict__ Wk,
    const float* __restrict__ Wv,
    char* __restrict__ ws)
{
    h2* wqH = (h2*)(ws + WS_WQ);
    float* kvw = (float*)(ws + WS_KVW);
    const int b = blockIdx.x;
    const int tid = threadIdx.x;

    // Wq rows -> f16 pairs (2 rows x 48 pairs = 96 work items)
    if (tid < 2 * (TD / 2)) {
        int r = 2 * b + tid / (TD / 2);
        int c = tid % (TD / 2);
        float2 f = ((const float2*)(Wq + r * TD))[c];
        wqH[r * (TD / 2) + c] = pack_h2(f.x, f.y);
    }
    // kvw[d][4+n] = tanh(tanh(tokens[n] . Wk[d]))  (pre-tanh'd, addition formula)
    if (tid < 2 * NT) {
        int d = 2 * b + tid / NT;
        int n = tid % NT;
        const float4* tr = (const float4*)(tokens + n * TD);
        const float4* wr = (const float4*)(Wk + d * TD);
        float acc = 0.0f;
        #pragma unroll
        for (int j = 0; j < TD / 4; ++j) {
            float4 a = tr[j];
            float4 w = wr[j];
            acc = fmaf(a.x, w.x, acc);
            acc = fmaf(a.y, w.y, acc);
            acc = fmaf(a.z, w.z, acc);
            acc = fmaf(a.w, w.w, acc);
        }
        kvw[d * 16 + 4 + n] = fast_tanh(fast_tanh(acc));
    }
    // kvw[d][h] = Wv[h][d]; zero the pad
    if (tid < 2 * NH) {
        int d = 2 * b + (tid >> 2);
        int h = tid & 3;
        kvw[d * 16 + h] = Wv[h * TD + d];
    }
    if (tid < 2 * 2) {
        int d = 2 * b + (tid >> 1);
        kvw[d * 16 + 14 + (tid & 1)] = 0.0f;
    }
}

// ---- main kernel: 8 lanes/position, 8 blocks/CU (tail-free single round) ----
__global__ __launch_bounds__(TPB, 8) void gst_main(
    const float* __restrict__ ref_emb,
    const float* __restrict__ tokens,
    const char* __restrict__ ws,
    float* __restrict__ out)
{
    __shared__ __align__(16) h2 wqS[TD * (TD / 2)]; // 18432 B only

    const int tid = threadIdx.x;
    const int pos = (blockIdx.x * TPB + tid) >> 3;
    const int l = tid & 7;
    const float* kvw = (const float*)(ws + WS_KVW); // L1-resident 6 KB table

    // prefetch this lane's x twelfth (3 float4), overlapping the LDS copy
    const float4* xr = (const float4*)(ref_emb + (size_t)pos * TD + l * XPL);
    float4 x0 = xr[0], x1 = xr[1], x2 = xr[2];

    // stage wq -> LDS: linear copy, 1152 float4 over 256 threads
    {
        const float4* src = (const float4*)ws;
        float4* dst = (float4*)wqS;
        #pragma unroll
        for (int i = 0; i < 4; ++i)
            dst[tid + i * TPB] = src[tid + i * TPB];
        if (tid < 128) dst[tid + 4 * TPB] = src[tid + 4 * TPB];
    }

    h2 xh[6];
    xh[0] = pack_h2(x0.x, x0.y); xh[1] = pack_h2(x0.z, x0.w);
    xh[2] = pack_h2(x1.x, x1.y); xh[3] = pack_h2(x1.z, x1.w);
    xh[4] = pack_h2(x2.x, x2.y); xh[5] = pack_h2(x2.z, x2.w);
    __syncthreads();

    float logits[NT][NH];
    #pragma unroll
    for (int n = 0; n < NT; ++n)
        #pragma unroll
        for (int h = 0; h < NH; ++h) logits[n][h] = 0.0f;

    // ---- fused q + s phase: 12 groups of 8 d's ----
    #pragma unroll 2
    for (int cc = 0; cc < 12; ++cc) {
        // partial dots, row-relative indexing: p[i] = partial of row (l^i)
        float p[8];
        #pragma unroll
        for (int i = 0; i < 8; ++i) {
            const h2* w = &wqS[(8 * cc + (l ^ i)) * (TD / 2) + l * (XPL / 2)];
            float a = 0.0f;
            #pragma unroll
            for (int j = 0; j < XPL / 2; ++j) a = dot2acc(xh[j], w[j], a);
            p[i] = a;
        }
        // select-free xor butterfly: p[i] holds row l^i -> partner has it at i^m
        p[0] += __shfl_xor(p[1], 1);
        p[2] += __shfl_xor(p[3], 1);
        p[4] += __shfl_xor(p[5], 1);
        p[6] += __shfl_xor(p[7], 1);
        p[0] += __shfl_xor(p[2], 2);
        p[4] += __shfl_xor(p[6], 2);
        p[0] += __shfl_xor(p[4], 4);

        // tq = tanh(q), q = tanh(raw)   (for the exact tanh addition formula)
        const float tq = fast_tanh(fast_tanh(p[0]));

        // s phase for d = 8*cc + l: s = (tq + tk)/(1 + tq*tk) = tanh(q + k)
        const int d = 8 * cc + l;
        const float* row = kvw + d * 16;
        const float4 wv = *(const float4*)(row);     // wv0..3
        const float4 ka = *(const float4*)(row + 4); // kv0..3
        const float4 kb = *(const float4*)(row + 8); // kv4..7
        const float2 kc = *(const float2*)(row + 12);// kv8..9
        const float kv[NT] = {ka.x, ka.y, ka.z, ka.w, kb.x, kb.y, kb.z, kb.w, kc.x, kc.y};
        #pragma unroll
        for (int n = 0; n < NT; ++n) {
            float num = tq + kv[n];
            float den = fmaf(tq, kv[n], 1.0f);
            float s = num * __builtin_amdgcn_rcpf(den);
            logits[n][0] = fmaf(s, wv.x, logits[n][0]);
            logits[n][1] = fmaf(s, wv.y, logits[n][1]);
            logits[n][2] = fmaf(s, wv.z, logits[n][2]);
            logits[n][3] = fmaf(s, wv.w, logits[n][3]);
        }
    }

    // ---- logits reduce-scatter over the 8-lane group:
    //      lane ends with lh[n] = fully-reduced logits[n][h = l&3] ----
    const bool myb0 = (l & 1) != 0;
    const bool myb1 = (l & 2) != 0;
    float lh[NT];
    #pragma unroll
    for (int n = 0; n < NT; ++n) {
        float L0 = logits[n][0], L1 = logits[n][1];
        float L2 = logits[n][2], L3 = logits[n][3];
        // full round xor4 (lanes l, l^4 need the same h)
        L0 += __shfl_xor(L0, 4);
        L1 += __shfl_xor(L1, 4);
        L2 += __shfl_xor(L2, 4);
        L3 += __shfl_xor(L3, 4);
        // reduce-scatter xor2: keep h-pair with bit1 == myb1, send partner's
        float m0 = myb1 ? L2 : L0, m1 = myb1 ? L3 : L1;
        float t0 = myb1 ? L0 : L2, t1 = myb1 ? L1 : L3;
        m0 += __shfl_xor(t0, 2);
        m1 += __shfl_xor(t1, 2);
        // reduce-scatter xor1: keep h with bit0 == myb0
        float mm = myb0 ? m1 : m0, tt = myb0 ? m0 : m1;
        lh[n] = mm + __shfl_xor(tt, 1);
    }

    // ---- per-lane softmax for head h=l&3; then wn[n] = mean_h attn ----
    float m = lh[0];
    #pragma unroll
    for (int n = 1; n < NT; ++n) m = fmaxf(m, lh[n]);
    float e[NT];
    float ssum = 0.0f;
    #pragma unroll
    for (int n = 0; n < NT; ++n) {
        e[n] = __expf(lh[n] - m);
        ssum += e[n];
    }
    const float inv = 0.25f * __builtin_amdgcn_rcpf(ssum);
    float wn[NT];
    #pragma unroll
    for (int n = 0; n < NT; ++n) {
        float v = e[n] * inv;      // 0.25 * attn[n][l&3]
        v += __shfl_xor(v, 1);     // sum heads differing in bit0
        v += __shfl_xor(v, 2);     // sum heads differing in bit1
        wn[n] = v;                 // mean_h attn[n][h], replicated
    }

    // ---- style + store, coalesced: lane handles float4-index l + 8*jj ----
    float4* ob = (float4*)(out + (size_t)pos * TD);
    const float4* t4 = (const float4*)tokens;
    #pragma unroll
    for (int jj = 0; jj < 3; ++jj) {
        const int d4 = l + 8 * jj;
        float4 o = make_float4(0.f, 0.f, 0.f, 0.f);
        #pragma unroll
        for (int n = 0; n < NT; ++n) {
            float4 t = t4[n * (TD / 4) + d4];
            o.x = fmaf(wn[n], t.x, o.x);
            o.y = fmaf(wn[n], t.y, o.y);
            o.z = fmaf(wn[n], t.z, o.z);
            o.w = fmaf(wn[n], t.w, o.w);
        }
        ob[d4] = o;
    }
}

extern "C" void kernel_launch(void* const* d_in, const int* in_sizes, int n_in,
                              void* d_out, int out_size, void* d_ws, size_t ws_size,
                              hipStream_t stream) {
    const float* ref_emb = (const float*)d_in[0];
    const float* tokens  = (const float*)d_in[1];
    const float* Wq      = (const float*)d_in[2];
    const float* Wk      = (const float*)d_in[3];
    const float* Wv      = (const float*)d_in[4];
    float* out = (float*)d_out;

    gst_prep<<<TD / 2, 256, 0, stream>>>(tokens, Wq, Wk, Wv, (char*)d_ws);
    gst_main<<<(NPOS * LPP) / TPB, TPB, 0, stream>>>(ref_emb, tokens,
                                                     (const char*)d_ws, out);
}

// Round 9
// 55.357 us; speedup vs baseline: 3.6618x; 3.6618x over previous
//
#include <hip/hip_runtime.h>
#include <cstddef>

#define NT 10            // NUM_TOKENS
#define TD 96            // TOKEN_DIM == REF_DIM
#define NH 4             // NUM_HEADS
#define NPOS (32 * 2048) // B*T positions
#define TPB 256
#define LPP 8            // lanes per position
#define XPL 12           // x elems per lane (TD / LPP)

// workspace layout (bytes)
#define WS_WQ 0          // h2    wqH[96][48]            (18432 B) -> staged to LDS
#define WS_KVW 18432     // float kvw[96][16]             ( 6144 B) -> read via L1
                         //   row d: [wv0..3 | kv0..9 | pad pad]
#define WS_BYTES 24576

typedef _Float16 h2 __attribute__((ext_vector_type(2)));

__device__ __forceinline__ h2 pack_h2(float a, float b) {
    return __builtin_bit_cast(h2, __builtin_amdgcn_cvt_pkrtz(a, b));
}

__device__ __forceinline__ float fast_tanh(float x) {
    // tanh(x) = 1 - 2/(exp(2x)+1); exact limits at +/-inf, ~1e-6 rel error
    float e = __expf(2.0f * x);
    return 1.0f - 2.0f * __builtin_amdgcn_rcpf(e + 1.0f);
}

__device__ __forceinline__ float dot2acc(h2 a, h2 b, float c) {
#if __has_builtin(__builtin_amdgcn_fdot2)
    return __builtin_amdgcn_fdot2(a, b, c, false);
#else
    c = fmaf((float)a[0], (float)b[0], c);
    return fmaf((float)a[1], (float)b[1], c);
#endif
}

// ---- prep kernel: 48 blocks, block b owns d-slice [2b, 2b+2) ----
__global__ __launch_bounds__(256) void gst_prep(
    const float* __restrict__ tokens,
    const float* __restrict__ Wq,
    const float* __restrict__ Wk,
    const float* __restrict__ Wv,
    char* __restrict__ ws)
{
    h2* wqH = (h2*)(ws + WS_WQ);
    float* kvw = (float*)(ws + WS_KVW);
    const int b = blockIdx.x;
    const int tid = threadIdx.x;

    // Wq rows -> f16 pairs (2 rows x 48 pairs = 96 work items)
    if (tid < 2 * (TD / 2)) {
        int r = 2 * b + tid / (TD / 2);
        int c = tid % (TD / 2);
        float2 f = ((const float2*)(Wq + r * TD))[c];
        wqH[r * (TD / 2) + c] = pack_h2(f.x, f.y);
    }
    // kvw[d][4+n] = tanh(tanh(tokens[n] . Wk[d]))  (pre-tanh'd, addition formula)
    if (tid < 2 * NT) {
        int d = 2 * b + tid / NT;
        int n = tid % NT;
        const float4* tr = (const float4*)(tokens + n * TD);
        const float4* wr = (const float4*)(Wk + d * TD);
        float acc = 0.0f;
        #pragma unroll
        for (int j = 0; j < TD / 4; ++j) {
            float4 a = tr[j];
            float4 w = wr[j];
            acc = fmaf(a.x, w.x, acc);
            acc = fmaf(a.y, w.y, acc);
            acc = fmaf(a.z, w.z, acc);
            acc = fmaf(a.w, w.w, acc);
        }
        kvw[d * 16 + 4 + n] = fast_tanh(fast_tanh(acc));
    }
    // kvw[d][h] = Wv[h][d]; zero the pad
    if (tid < 2 * NH) {
        int d = 2 * b + (tid >> 2);
        int h = tid & 3;
        kvw[d * 16 + h] = Wv[h * TD + d];
    }
    if (tid < 2 * 2) {
        int d = 2 * b + (tid >> 1);
        kvw[d * 16 + 14 + (tid & 1)] = 0.0f;
    }
}

// ---- main kernel: 8 lanes/position; LDS 18432 B -> HW fits 8 blocks/CU,
//      grid 2048 = 8 x 256 CU exactly (tail-free single round).
//      launch_bounds min-waves kept at 6: value 8 provably collapses the
//      allocator to 32 VGPR + full spill (R7/R8); 6 compiles to ~40, and the
//      runtime occupancy is LDS/VGPR-bound, not bound by this hint. ----
__global__ __launch_bounds__(TPB, 6) void gst_main(
    const float* __restrict__ ref_emb,
    const float* __restrict__ tokens,
    const char* __restrict__ ws,
    float* __restrict__ out)
{
    __shared__ __align__(16) h2 wqS[TD * (TD / 2)]; // 18432 B only

    const int tid = threadIdx.x;
    const int pos = (blockIdx.x * TPB + tid) >> 3;
    const int l = tid & 7;
    const float* kvw = (const float*)(ws + WS_KVW); // L1-resident 6 KB table

    // prefetch this lane's x twelfth (3 float4), overlapping the LDS copy
    const float4* xr = (const float4*)(ref_emb + (size_t)pos * TD + l * XPL);
    float4 x0 = xr[0], x1 = xr[1], x2 = xr[2];

    // stage wq -> LDS: linear copy, 1152 float4 over 256 threads
    {
        const float4* src = (const float4*)ws;
        float4* dst = (float4*)wqS;
        #pragma unroll
        for (int i = 0; i < 4; ++i)
            dst[tid + i * TPB] = src[tid + i * TPB];
        if (tid < 128) dst[tid + 4 * TPB] = src[tid + 4 * TPB];
    }

    h2 xh[6];
    xh[0] = pack_h2(x0.x, x0.y); xh[1] = pack_h2(x0.z, x0.w);
    xh[2] = pack_h2(x1.x, x1.y); xh[3] = pack_h2(x1.z, x1.w);
    xh[4] = pack_h2(x2.x, x2.y); xh[5] = pack_h2(x2.z, x2.w);
    __syncthreads();

    float logits[NT][NH];
    #pragma unroll
    for (int n = 0; n < NT; ++n)
        #pragma unroll
        for (int h = 0; h < NH; ++h) logits[n][h] = 0.0f;

    // ---- fused q + s phase: 12 groups of 8 d's ----
    #pragma unroll 2
    for (int cc = 0; cc < 12; ++cc) {
        // partial dots, row-relative indexing: p[i] = partial of row (l^i)
        float p[8];
        #pragma unroll
        for (int i = 0; i < 8; ++i) {
            const h2* w = &wqS[(8 * cc + (l ^ i)) * (TD / 2) + l * (XPL / 2)];
            float a = 0.0f;
            #pragma unroll
            for (int j = 0; j < XPL / 2; ++j) a = dot2acc(xh[j], w[j], a);
            p[i] = a;
        }
        // select-free xor butterfly: p[i] holds row l^i -> partner has it at i^m
        p[0] += __shfl_xor(p[1], 1);
        p[2] += __shfl_xor(p[3], 1);
        p[4] += __shfl_xor(p[5], 1);
        p[6] += __shfl_xor(p[7], 1);
        p[0] += __shfl_xor(p[2], 2);
        p[4] += __shfl_xor(p[6], 2);
        p[0] += __shfl_xor(p[4], 4);

        // tq = tanh(q), q = tanh(raw)   (for the exact tanh addition formula)
        const float tq = fast_tanh(fast_tanh(p[0]));

        // s phase for d = 8*cc + l: s = (tq + tk)/(1 + tq*tk) = tanh(q + k)
        const int d = 8 * cc + l;
        const float* row = kvw + d * 16;
        const float4 wv = *(const float4*)(row);     // wv0..3
        const float4 ka = *(const float4*)(row + 4); // kv0..3
        const float4 kb = *(const float4*)(row + 8); // kv4..7
        const float2 kc = *(const float2*)(row + 12);// kv8..9
        const float kv[NT] = {ka.x, ka.y, ka.z, ka.w, kb.x, kb.y, kb.z, kb.w, kc.x, kc.y};
        #pragma unroll
        for (int n = 0; n < NT; ++n) {
            float num = tq + kv[n];
            float den = fmaf(tq, kv[n], 1.0f);
            float s = num * __builtin_amdgcn_rcpf(den);
            logits[n][0] = fmaf(s, wv.x, logits[n][0]);
            logits[n][1] = fmaf(s, wv.y, logits[n][1]);
            logits[n][2] = fmaf(s, wv.z, logits[n][2]);
            logits[n][3] = fmaf(s, wv.w, logits[n][3]);
        }
    }

    // ---- logits reduce-scatter over the 8-lane group:
    //      lane ends with lh[n] = fully-reduced logits[n][h = l&3] ----
    const bool myb0 = (l & 1) != 0;
    const bool myb1 = (l & 2) != 0;
    float lh[NT];
    #pragma unroll
    for (int n = 0; n < NT; ++n) {
        float L0 = logits[n][0], L1 = logits[n][1];
        float L2 = logits[n][2], L3 = logits[n][3];
        // full round xor4 (lanes l, l^4 need the same h)
        L0 += __shfl_xor(L0, 4);
        L1 += __shfl_xor(L1, 4);
        L2 += __shfl_xor(L2, 4);
        L3 += __shfl_xor(L3, 4);
        // reduce-scatter xor2: keep h-pair with bit1 == myb1, send partner's
        float m0 = myb1 ? L2 : L0, m1 = myb1 ? L3 : L1;
        float t0 = myb1 ? L0 : L2, t1 = myb1 ? L1 : L3;
        m0 += __shfl_xor(t0, 2);
        m1 += __shfl_xor(t1, 2);
        // reduce-scatter xor1: keep h with bit0 == myb0
        float mm = myb0 ? m1 : m0, tt = myb0 ? m0 : m1;
        lh[n] = mm + __shfl_xor(tt, 1);
    }

    // ---- per-lane softmax for head h=l&3; then wn[n] = mean_h attn ----
    float m = lh[0];
    #pragma unroll
    for (int n = 1; n < NT; ++n) m = fmaxf(m, lh[n]);
    float e[NT];
    float ssum = 0.0f;
    #pragma unroll
    for (int n = 0; n < NT; ++n) {
        e[n] = __expf(lh[n] - m);
        ssum += e[n];
    }
    const float inv = 0.25f * __builtin_amdgcn_rcpf(ssum);
    float wn[NT];
    #pragma unroll
    for (int n = 0; n < NT; ++n) {
        float v = e[n] * inv;      // 0.25 * attn[n][l&3]
        v += __shfl_xor(v, 1);     // sum heads differing in bit0
        v += __shfl_xor(v, 2);     // sum heads differing in bit1
        wn[n] = v;                 // mean_h attn[n][h], replicated
    }

    // ---- style + store, coalesced: lane handles float4-index l + 8*jj ----
    float4* ob = (float4*)(out + (size_t)pos * TD);
    const float4* t4 = (const float4*)tokens;
    #pragma unroll
    for (int jj = 0; jj < 3; ++jj) {
        const int d4 = l + 8 * jj;
        float4 o = make_float4(0.f, 0.f, 0.f, 0.f);
        #pragma unroll
        for (int n = 0; n < NT; ++n) {
            float4 t = t4[n * (TD / 4) + d4];
            o.x = fmaf(wn[n], t.x, o.x);
            o.y = fmaf(wn[n], t.y, o.y);
            o.z = fmaf(wn[n], t.z, o.z);
            o.w = fmaf(wn[n], t.w, o.w);
        }
        ob[d4] = o;
    }
}

extern "C" void kernel_launch(void* const* d_in, const int* in_sizes, int n_in,
                              void* d_out, int out_size, void* d_ws, size_t ws_size,
                              hipStream_t stream) {
    const float* ref_emb = (const float*)d_in[0];
    const float* tokens  = (const float*)d_in[1];
    const float* Wq      = (const float*)d_in[2];
    const float* Wk      = (const float*)d_in[3];
    const float* Wv      = (const float*)d_in[4];
    float* out = (float*)d_out;

    gst_prep<<<TD / 2, 256, 0, stream>>>(tokens, Wq, Wk, Wv, (char*)d_ws);
    gst_main<<<(NPOS * LPP) / TPB, TPB, 0, stream>>>(ref_emb, tokens,
                                                     (const char*)d_ws, out);
}